// Round 4
// baseline (132.289 us; speedup 1.0000x reference)
//
#include <hip/hip_runtime.h>

// SupConLoss, B=8192, D=128, T=5.0
// v5: symmetric-triangle tiling + max-free formulation.
//   - sim is symmetric: each off-diag e_ij computed ONCE (256x64 tiles below the
//     diagonal), credited to Z_i (row-side) and Z_j (col-side) via atomicAdd.
//     Tiles overlapping the diagonal 256-block computed full, row-side only.
//   - m cancels algebraically: term = (A-cnt*m)/cnt - log(1e-12 + Z*e^{C40-m})
//     is exact for ANY m (m only perturbs the 1e-12 term) -> use m~ = ||f||^2/T.
//     No max tracking anywhere; partials are pure sums.
//   - B tiles in slot-linear LDS (conflict-free ds_read_b128 by construction),
//     staged once per block via global_load_lds, ONE barrier per block.
// Inner loop per element: fma + exp2 + 2 adds   (half the elements of v4).

#define BN 8192
#define DK 128
#define INV_T 0.2f
#define C1F 0.28853901f     // INV_T * log2(e)
#define C40F 27.7258872f    // 40 * ln(2)

#define NBX    32           // 256-row chunks
#define TILES  2112         // sum_{bx=0}^{31} (4*bx+4)
#define RIDERS 32
#define PSLOTS 32

#define NCLS 100
#define PB 128              // prep blocks
#define PROWS (BN / PB)     // 64

// workspace layout (bytes)
#define OFF_FB    0                                 // 2 MB bf16 features
#define OFF_PART  (2 * 1024 * 1024)                 // 1 MB float [PSLOTS][BN]
#define OFF_GP    (OFF_PART + PSLOTS * BN * 4)      // 6.55 MB G partials [PB][100][128]
#define OFF_HISTP (OFF_GP + PB * NCLS * DK * 4)     // 51 KB hist partials
#define OFF_G     (OFF_HISTP + PB * NCLS * 4)       // class sums
#define OFF_HIST  (OFF_G + NCLS * DK * 4)           // hist
#define OFF_BSUM  (OFF_HIST + 512)                  // block sums
#define OFF_CTR   (OFF_BSUM + 256)                  // arrival counter

typedef __attribute__((ext_vector_type(8))) short bf16x8;   // 8 bf16 = 4 VGPRs
typedef __attribute__((ext_vector_type(4))) float f32x4;

__device__ __forceinline__ unsigned short f2bf(float f) {
    unsigned u = __builtin_bit_cast(unsigned, f);
    u += 0x7fffu + ((u >> 16) & 1u);
    return (unsigned short)(u >> 16);
}

__device__ __forceinline__ float fexp2(float x) {
#if __has_builtin(__builtin_amdgcn_exp2f)
    return __builtin_amdgcn_exp2f(x);
#else
    float r; asm("v_exp_f32 %0, %1" : "=v"(r) : "v"(x)); return r;
#endif
}

__device__ __forceinline__ void load_lds16(const void* g, void* l) {
    __builtin_amdgcn_global_load_lds(
        (const __attribute__((address_space(1))) unsigned int*)g,
        (__attribute__((address_space(3))) unsigned int*)l, 16, 0, 0);
}

// prep: cast to bf16, zero part, per-block label hist + class-sum partials
__global__ __launch_bounds__(256) void prep_kernel(const float* __restrict__ F,
                                                   const int* __restrict__ labels,
                                                   unsigned short* __restrict__ Fb,
                                                   float* __restrict__ part,
                                                   float* __restrict__ Gp,
                                                   int* __restrict__ histp,
                                                   unsigned int* __restrict__ ctr) {
    const int t  = threadIdx.x;
    const int b  = blockIdx.x;
    const int r0 = b * PROWS;

    if (b == 0 && t == 0) *ctr = 0u;   // re-arm finalize's last-block counter

    // zero part: 65536 float4 / 128 blocks = 512 per block
    {
        float4* pz = (float4*)part + (size_t)b * (PSLOTS * BN / 4 / PB);
#pragma unroll
        for (int k = 0; k < PSLOTS * BN / 4 / PB / 256; ++k)   // 2
            pz[k * 256 + t] = make_float4(0.f, 0.f, 0.f, 0.f);
    }

    // cast: 64 rows = 2048 float4 per block
    const float4* F4  = (const float4*)F + (size_t)b * (PROWS * DK / 4);
    ushort4*      Fb4 = (ushort4*)Fb + (size_t)b * (PROWS * DK / 4);
#pragma unroll
    for (int k = 0; k < PROWS * DK / 4 / 256; ++k) {   // 8
        float4 v = F4[k * 256 + t];
        ushort4 o;
        o.x = f2bf(v.x); o.y = f2bf(v.y); o.z = f2bf(v.z); o.w = f2bf(v.w);
        Fb4[k * 256 + t] = o;
    }

    __shared__ int   ll[PROWS];
    __shared__ int   lh[NCLS];
    __shared__ float gl[2][NCLS][DK];   // 102.4 KB: two half-row partial tables
    float4* gl4 = (float4*)gl;
    if (t < NCLS) lh[t] = 0;
    if (t < PROWS) ll[t] = labels[r0 + t];
#pragma unroll
    for (int k = 0; k < 2 * NCLS * DK / 4 / 256; ++k)   // 25
        gl4[k * 256 + t] = make_float4(0.f, 0.f, 0.f, 0.f);
    __syncthreads();

    if (t < PROWS) atomicAdd(&lh[ll[t]], 1);

    // class-sum partials: 256 threads = 2 halves x 128 columns, 32 rows each
    {
        const int half = t >> 7, col = t & 127;
        const int rb   = half * (PROWS / 2);
        for (int rr = 0; rr < PROWS / 2; ++rr) {
            const int lr = rb + rr;
            gl[half][ll[lr]][col] += F[(size_t)(r0 + lr) * DK + col];
        }
    }
    __syncthreads();

    if (t < NCLS) histp[b * NCLS + t] = lh[t];
    const float* gl0 = (const float*)gl;
#pragma unroll
    for (int k = 0; k < NCLS * DK / 256; ++k) {   // 50
        const int idx = k * 256 + t;
        Gp[(size_t)b * (NCLS * DK) + idx] = gl0[idx] + gl0[NCLS * DK + idx];
    }
}

// one 256-row x 64-col tile: rows chunk bx (256), cols chunk cy (64)
template <bool DIAGT>
__device__ __forceinline__ void supcon_tile(const short* __restrict__ Fb,
                                            float* __restrict__ part,
                                            int bx, int cy, char* smem) {
    const int t    = threadIdx.x;
    const int wave = t >> 6, lane = t & 63;
    const int quad = lane >> 4, l16 = lane & 15;
    const int rowBase = bx * 256 + wave * 64;
    const int colBase = cy * 64;

    // stage all 4 B tiles (16 cols x 128 k = 4 KB each), slot-linear layout:
    // LDS slot s = (kt*4+quad)*16 + col  holds  Fb[colBase16+col][kt*32+quad*8 ..+8]
    // -> per-lane pre-permuted GLOBAL source, linear LDS dest (rule #21),
    //    reads are 128B-contiguous per 8 lanes: zero bank conflicts.
    {
        const char* Btile = (const char*)Fb + (size_t)colBase * 256;
        const int   s     = wave * 64 + lane;
        const int   gso   = (s & 15) * 256 + (s >> 6) * 64 + ((s >> 4) & 3) * 16;
        char*       ldsw  = smem + wave * 1024;   // wave-uniform base
#pragma unroll
        for (int jt = 0; jt < 4; ++jt)
            load_lds16(Btile + jt * 4096 + gso, ldsw + jt * 4096);
    }

    // A fragments: 64 rows x K=128 resident in registers for the whole tile
    bf16x8 a[4][4];
#pragma unroll
    for (int rt = 0; rt < 4; ++rt)
#pragma unroll
        for (int kt = 0; kt < 4; ++kt)
            a[rt][kt] = *(const bf16x8*)(Fb + (size_t)(rowBase + rt * 16 + l16) * DK
                                            + kt * 32 + quad * 8);

    float Zs[4][4];
#pragma unroll
    for (int rt = 0; rt < 4; ++rt)
#pragma unroll
        for (int r = 0; r < 4; ++r) Zs[rt][r] = 0.f;

    __syncthreads();   // single barrier: all tiles staged

    const int roffb = quad * 256 + l16 * 16;
#pragma unroll
    for (int jt = 0; jt < 4; ++jt) {
        bf16x8 bb[4];
#pragma unroll
        for (int kt = 0; kt < 4; ++kt)
            bb[kt] = *(const bf16x8*)(smem + jt * 4096 + kt * 1024 + roffb);
        float Zc = 0.f;
#pragma unroll
        for (int rt = 0; rt < 4; ++rt) {
            f32x4 acc = {0.f, 0.f, 0.f, 0.f};
#pragma unroll
            for (int kt = 0; kt < 4; ++kt)
                acc = __builtin_amdgcn_mfma_f32_16x16x32_bf16(a[rt][kt], bb[kt], acc, 0, 0, 0);
#pragma unroll
            for (int r = 0; r < 4; ++r) {
                float e = fexp2(fmaf(acc[r], C1F, -40.0f));   // fixed-scale exp
                if (DIAGT) {
                    if (colBase + jt * 16 + l16 == rowBase + rt * 16 + quad * 4 + r)
                        e = 0.f;                               // Z excludes diagonal
                }
                Zs[rt][r] += e;    // row-side
                Zc       += e;    // col-side (dead-code-eliminated if DIAGT)
            }
        }
        if (!DIAGT) {   // col-side: Z_j partial over this tile's 256 rows
            Zc += __shfl_xor(Zc, 16);
            Zc += __shfl_xor(Zc, 32);
            if (quad == 0)
                atomicAdd(&part[(size_t)bx * BN + colBase + jt * 16 + l16], Zc);
        }
    }

    // row-side: merge 16 col-lanes, slot = col-chunk-256 = cy>>2
    const int slot = cy >> 2;
#pragma unroll
    for (int rt = 0; rt < 4; ++rt)
#pragma unroll
        for (int r = 0; r < 4; ++r) {
            float zz = Zs[rt][r];
#pragma unroll
            for (int h = 1; h < 16; h <<= 1) zz += __shfl_xor(zz, h);
            if (l16 == 0)
                atomicAdd(&part[(size_t)slot * BN + rowBase + rt * 16 + quad * 4 + r], zz);
        }
}

__global__ __launch_bounds__(256) void supcon_main(const short* __restrict__ Fb,
                                                   float* __restrict__ part,
                                                   const float* __restrict__ Gp,
                                                   const int* __restrict__ histp,
                                                   float* __restrict__ G,
                                                   int* __restrict__ hist) {
    __shared__ alignas(16) char smem[16384];
    const int bid = blockIdx.x;
    if (bid >= TILES) {   // 32 rider blocks: reduce G/hist partials
        const int base = (bid - TILES) * 256 + threadIdx.x;
        for (int idx = base; idx < NCLS * DK + NCLS; idx += RIDERS * 256) {
            if (idx < NCLS * DK) {
                float s = 0.f;
#pragma unroll 8
                for (int p = 0; p < PB; ++p) s += Gp[(size_t)p * (NCLS * DK) + idx];
                G[idx] = s;
            } else {
                const int c = idx - NCLS * DK;
                int s = 0;
#pragma unroll 8
                for (int p = 0; p < PB; ++p) s += histp[p * NCLS + c];
                hist[c] = s;
            }
        }
        return;
    }
    // decode triangular tile id: start(bx) = 2*bx*(bx+1), cy in [0, 4*bx+4)
    float sq = sqrtf(2.0f * (float)bid + 1.0f);
    int bx = (int)((sq - 1.0f) * 0.5f);
    while (2 * (bx + 1) * (bx + 2) <= bid) ++bx;
    while (bx > 0 && 2 * bx * (bx + 1) > bid) --bx;
    const int cy = bid - 2 * bx * (bx + 1);
    if (cy >= 4 * bx) supcon_tile<true >(Fb, part, bx, cy, smem);  // overlaps diagonal
    else              supcon_tile<false>(Fb, part, bx, cy, smem);  // strictly below
}

__global__ __launch_bounds__(256) void supcon_finalize(const float* __restrict__ F,
                                                       const int* __restrict__ labels,
                                                       const float* __restrict__ part,
                                                       const float* __restrict__ G,
                                                       const int* __restrict__ hist,
                                                       float* __restrict__ bsums,
                                                       unsigned int* __restrict__ ctr,
                                                       float* __restrict__ out) {
    const int t = threadIdx.x;
    const int i = blockIdx.x * 256 + t;

    float Zm = 0.f;
#pragma unroll 8
    for (int c = 0; c < PSLOTS; ++c) Zm += part[(size_t)c * BN + i];

    const int   lbl = labels[i];
    const float cnt = (float)(hist[lbl] - 1);

    const float4* fr = (const float4*)(F + (size_t)i * DK);
    const float4* gr = (const float4*)(G + lbl * DK);
    float dot = 0.f, nrm = 0.f;
#pragma unroll 8
    for (int k = 0; k < DK / 4; ++k) {
        const float4 av = fr[k], gv = gr[k];
        dot += av.x * gv.x + av.y * gv.y + av.z * gv.z + av.w * gv.w;
        nrm += av.x * av.x + av.y * av.y + av.z * av.z + av.w * av.w;
    }

    // m~ = s_ii/T; exact for any m~ (m-dependence cancels outside the 1e-12 term)
    const float mt = nrm * INV_T;
    const float A  = (dot - nrm) * INV_T;
    float term = 0.f;
    if (cnt > 0.5f)
        term = (A - cnt * mt) / cnt - __logf(1e-12f + Zm * __expf(C40F - mt));

    float sum = term;
#pragma unroll
    for (int h = 1; h < 64; h <<= 1) sum += __shfl_xor(sum, h);
    __shared__ float ss[4];
    if ((t & 63) == 0) ss[t >> 6] = sum;
    __syncthreads();
    if (t == 0) {
        bsums[blockIdx.x] = ss[0] + ss[1] + ss[2] + ss[3];
        __threadfence();
        const unsigned old = atomicAdd(ctr, 1u);
        if (old == (BN / 256) - 1) {   // last block folds the final reduction
            __threadfence();
            float tot = 0.f;
            const volatile float* vb = bsums;
            for (int c = 0; c < BN / 256; ++c) tot += vb[c];
            out[0] = -tot * (1.0f / BN);
        }
    }
}

extern "C" void kernel_launch(void* const* d_in, const int* in_sizes, int n_in,
                              void* d_out, int out_size, void* d_ws, size_t ws_size,
                              hipStream_t stream) {
    const float* F      = (const float*)d_in[0];
    const int*   labels = (const int*)d_in[1];
    // d_in[2] (fac_label) is a no-op in the reference math.
    float* out = (float*)d_out;
    char*  ws  = (char*)d_ws;

    unsigned short* Fb    = (unsigned short*)(ws + OFF_FB);
    float*          part  = (float*)(ws + OFF_PART);
    float*          Gp    = (float*)(ws + OFF_GP);
    int*            histp = (int*)(ws + OFF_HISTP);
    float*          G     = (float*)(ws + OFF_G);
    int*            hist  = (int*)(ws + OFF_HIST);
    float*          bsums = (float*)(ws + OFF_BSUM);
    unsigned int*   ctr   = (unsigned int*)(ws + OFF_CTR);

    prep_kernel<<<PB, 256, 0, stream>>>(F, labels, Fb, part, Gp, histp, ctr);
    supcon_main<<<TILES + RIDERS, 256, 0, stream>>>((const short*)Fb, part,
                                                    Gp, histp, G, hist);
    supcon_finalize<<<BN / 256, 256, 0, stream>>>(F, labels, part, G, hist,
                                                  bsums, ctr, out);
}

// Round 5
// 118.240 us; speedup vs baseline: 1.1188x; 1.1188x over previous
//
#include <hip/hip_runtime.h>

// SupConLoss, B=8192, D=128, T=5.0
// v6: v3's fat-block structure + triangle symmetry at full 256x256 tile size +
//     4-tile staging groups (5 barriers/block instead of 17).
//   - 528 lower-triangle tiles (cy<=bx), 256 rows x 256 cols each, 16 jt steps.
//   - below-diag tiles: e_ij credited to row-side Z_i (slot cy, single-writer
//     plain store) AND col-side Z_j (slot bx, Zcol[16] regs -> end atomics).
//   - diag tiles (cy==bx): full square, row-side only, diagonal zeroed.
//   - B staged in 4-tile groups (16 KB) into 2 LDS halves; barrier drain has a
//     full 4-step compute shadow. Slot-linear LDS (0 bank conflicts, rule #21).
//   - max-free math: e = 2^(raw*invT*log2e - 40); m~ = ||f||^2/T in finalize
//     (exact: m only enters via the 1e-12 term).

#define BN 8192
#define DK 128
#define INV_T 0.2f
#define C1F 0.28853901f     // INV_T * log2(e)
#define C40F 27.7258872f    // 40 * ln(2)

#define TILES  528          // 32*33/2 lower-triangle 256x256 tiles
#define RIDERS 32
#define PSLOTS 32

#define NCLS 100
#define PB 128              // prep blocks
#define PROWS (BN / PB)     // 64

// workspace layout (bytes)
#define OFF_FB    0                                 // 2 MB bf16 features
#define OFF_PART  (2 * 1024 * 1024)                 // 1 MB float [PSLOTS][BN]
#define OFF_GP    (OFF_PART + PSLOTS * BN * 4)      // 6.55 MB G partials [PB][100][128]
#define OFF_HISTP (OFF_GP + PB * NCLS * DK * 4)     // 51 KB hist partials
#define OFF_G     (OFF_HISTP + PB * NCLS * 4)       // class sums
#define OFF_HIST  (OFF_G + NCLS * DK * 4)           // hist
#define OFF_BSUM  (OFF_HIST + 512)                  // block sums
#define OFF_CTR   (OFF_BSUM + 256)                  // arrival counter

typedef __attribute__((ext_vector_type(8))) short bf16x8;   // 8 bf16 = 4 VGPRs
typedef __attribute__((ext_vector_type(4))) float f32x4;

__device__ __forceinline__ unsigned short f2bf(float f) {
    unsigned u = __builtin_bit_cast(unsigned, f);
    u += 0x7fffu + ((u >> 16) & 1u);
    return (unsigned short)(u >> 16);
}

__device__ __forceinline__ float fexp2(float x) {
#if __has_builtin(__builtin_amdgcn_exp2f)
    return __builtin_amdgcn_exp2f(x);
#else
    float r; asm("v_exp_f32 %0, %1" : "=v"(r) : "v"(x)); return r;
#endif
}

__device__ __forceinline__ void load_lds16(const void* g, void* l) {
    __builtin_amdgcn_global_load_lds(
        (const __attribute__((address_space(1))) unsigned int*)g,
        (__attribute__((address_space(3))) unsigned int*)l, 16, 0, 0);
}

// prep: cast to bf16, zero part, per-block label hist + class-sum partials
__global__ __launch_bounds__(256) void prep_kernel(const float* __restrict__ F,
                                                   const int* __restrict__ labels,
                                                   unsigned short* __restrict__ Fb,
                                                   float* __restrict__ part,
                                                   float* __restrict__ Gp,
                                                   int* __restrict__ histp,
                                                   unsigned int* __restrict__ ctr) {
    const int t  = threadIdx.x;
    const int b  = blockIdx.x;
    const int r0 = b * PROWS;

    if (b == 0 && t == 0) *ctr = 0u;   // re-arm finalize's last-block counter

    // zero part
    {
        float4* pz = (float4*)part + (size_t)b * (PSLOTS * BN / 4 / PB);
#pragma unroll
        for (int k = 0; k < PSLOTS * BN / 4 / PB / 256; ++k)   // 2
            pz[k * 256 + t] = make_float4(0.f, 0.f, 0.f, 0.f);
    }

    // cast: 64 rows = 2048 float4 per block
    const float4* F4  = (const float4*)F + (size_t)b * (PROWS * DK / 4);
    ushort4*      Fb4 = (ushort4*)Fb + (size_t)b * (PROWS * DK / 4);
#pragma unroll
    for (int k = 0; k < PROWS * DK / 4 / 256; ++k) {   // 8
        float4 v = F4[k * 256 + t];
        ushort4 o;
        o.x = f2bf(v.x); o.y = f2bf(v.y); o.z = f2bf(v.z); o.w = f2bf(v.w);
        Fb4[k * 256 + t] = o;
    }

    __shared__ int   ll[PROWS];
    __shared__ int   lh[NCLS];
    __shared__ float gl[2][NCLS][DK];   // 102.4 KB: two half-row partial tables
    float4* gl4 = (float4*)gl;
    if (t < NCLS) lh[t] = 0;
    if (t < PROWS) ll[t] = labels[r0 + t];
#pragma unroll
    for (int k = 0; k < 2 * NCLS * DK / 4 / 256; ++k)   // 25
        gl4[k * 256 + t] = make_float4(0.f, 0.f, 0.f, 0.f);
    __syncthreads();

    if (t < PROWS) atomicAdd(&lh[ll[t]], 1);

    // class-sum partials: 256 threads = 2 halves x 128 columns, 32 rows each
    {
        const int half = t >> 7, col = t & 127;
        const int rb   = half * (PROWS / 2);
        for (int rr = 0; rr < PROWS / 2; ++rr) {
            const int lr = rb + rr;
            gl[half][ll[lr]][col] += F[(size_t)(r0 + lr) * DK + col];
        }
    }
    __syncthreads();

    if (t < NCLS) histp[b * NCLS + t] = lh[t];
    const float* gl0 = (const float*)gl;
#pragma unroll
    for (int k = 0; k < NCLS * DK / 256; ++k) {   // 50
        const int idx = k * 256 + t;
        Gp[(size_t)b * (NCLS * DK) + idx] = gl0[idx] + gl0[NCLS * DK + idx];
    }
}

// one 256x256 tile at (bx, cy), cy <= bx
template <bool DIAGT>
__device__ __forceinline__ void supcon_tile(const short* __restrict__ Fb,
                                            float* __restrict__ part,
                                            int bx, int cy, char* smem) {
    const int t    = threadIdx.x;
    const int wave = t >> 6, lane = t & 63;
    const int quad = lane >> 4, l16 = lane & 15;
    const int rowBase = bx * 256 + wave * 64;
    const int colBase = cy * 256;

    // slot-linear LDS B tiles: tile jt is 4 KB; slot s=(kt*4+quad)*16+col holds
    // Fb[colBase + jt*16 + col][kt*32+quad*8 ..+8]. Per-lane pre-permuted GLOBAL
    // source (rule #21), linear LDS dest, conflict-free b128 reads.
    const char* Btile = (const char*)Fb + (size_t)colBase * 256;
    const int   gso   = (t & 15) * 256 + (t >> 6) * 64 + ((t >> 4) & 3) * 16;
    char*       ldsw  = smem + wave * 1024;   // wave-uniform dest base

    // stage group 0 (tiles 0..3) into half 0
#pragma unroll
    for (int tt = 0; tt < 4; ++tt)
        load_lds16(Btile + tt * 4096 + gso, ldsw + tt * 4096);

    // A fragments: 64 rows x K=128 resident in registers for the whole tile
    bf16x8 a[4][4];
#pragma unroll
    for (int rt = 0; rt < 4; ++rt)
#pragma unroll
        for (int kt = 0; kt < 4; ++kt)
            a[rt][kt] = *(const bf16x8*)(Fb + (size_t)(rowBase + rt * 16 + l16) * DK
                                            + kt * 32 + quad * 8);

    float Zs[4][4];
#pragma unroll
    for (int rt = 0; rt < 4; ++rt)
#pragma unroll
        for (int r = 0; r < 4; ++r) Zs[rt][r] = 0.f;
    float Zcol[16];   // col-side per-jt partials (statically indexed; g-loop unrolled)
#pragma unroll
    for (int j = 0; j < 16; ++j) Zcol[j] = 0.f;

    const int roffb = quad * 256 + l16 * 16;

    __syncthreads();   // group 0 staged (entry drain, once)

#pragma unroll
    for (int g = 0; g < 4; ++g) {
        // stage next group into the other half (full 4-step compute shadow)
        if (g < 3) {
            char* dsth = smem + ((g + 1) & 1) * 16384 + wave * 1024;
#pragma unroll
            for (int tt = 0; tt < 4; ++tt)
                load_lds16(Btile + (size_t)((g + 1) * 4 + tt) * 4096 + gso,
                           dsth + tt * 4096);
        }
        const char* srch = smem + (g & 1) * 16384;
#pragma unroll
        for (int tt = 0; tt < 4; ++tt) {
            const int jt = g * 4 + tt;
            bf16x8 bb[4];
#pragma unroll
            for (int kt = 0; kt < 4; ++kt)
                bb[kt] = *(const bf16x8*)(srch + tt * 4096 + kt * 1024 + roffb);
            float Zc = 0.f;
#pragma unroll
            for (int rt = 0; rt < 4; ++rt) {
                f32x4 acc = {0.f, 0.f, 0.f, 0.f};
#pragma unroll
                for (int kt = 0; kt < 4; ++kt)
                    acc = __builtin_amdgcn_mfma_f32_16x16x32_bf16(a[rt][kt], bb[kt],
                                                                  acc, 0, 0, 0);
#pragma unroll
                for (int r = 0; r < 4; ++r) {
                    float e = fexp2(fmaf(acc[r], C1F, -40.0f));
                    if (DIAGT) {
                        if (colBase + jt * 16 + l16 == rowBase + rt * 16 + quad * 4 + r)
                            e = 0.f;                       // Z excludes diagonal
                    }
                    Zs[rt][r] += e;                        // row-side
                    Zc += e;                               // col-side
                }
            }
            if (!DIAGT) {   // reduce over quad (rows of this wave), batch in regs
                Zc += __shfl_xor(Zc, 16);
                Zc += __shfl_xor(Zc, 32);
                Zcol[jt] = Zc;
            }
        }
        if (g < 3) __syncthreads();   // next half staged; this half free to overwrite
    }

    // row-side: slot cy is single-writer across the whole grid -> plain store
#pragma unroll
    for (int rt = 0; rt < 4; ++rt)
#pragma unroll
        for (int r = 0; r < 4; ++r) {
            float zz = Zs[rt][r];
#pragma unroll
            for (int h = 1; h < 16; h <<= 1) zz += __shfl_xor(zz, h);
            if (l16 == 0)
                part[(size_t)cy * BN + rowBase + rt * 16 + quad * 4 + r] = zz;
        }

    // col-side: slot bx; 4 waves collide on the same 256 addresses -> atomics
    if (!DIAGT) {
#pragma unroll
        for (int jt = 0; jt < 16; ++jt)
            if (quad == 0)
                atomicAdd(&part[(size_t)bx * BN + colBase + jt * 16 + l16], Zcol[jt]);
    }
}

__global__ __launch_bounds__(256) void supcon_main(const short* __restrict__ Fb,
                                                   float* __restrict__ part,
                                                   const float* __restrict__ Gp,
                                                   const int* __restrict__ histp,
                                                   float* __restrict__ G,
                                                   int* __restrict__ hist) {
    __shared__ alignas(16) char smem[32768];
    const int bid = blockIdx.x;
    if (bid >= TILES) {   // 32 rider blocks: reduce G/hist partials
        const int base = (bid - TILES) * 256 + threadIdx.x;
        for (int idx = base; idx < NCLS * DK + NCLS; idx += RIDERS * 256) {
            if (idx < NCLS * DK) {
                float s = 0.f;
#pragma unroll 8
                for (int p = 0; p < PB; ++p) s += Gp[(size_t)p * (NCLS * DK) + idx];
                G[idx] = s;
            } else {
                const int c = idx - NCLS * DK;
                int s = 0;
#pragma unroll 8
                for (int p = 0; p < PB; ++p) s += histp[p * NCLS + c];
                hist[c] = s;
            }
        }
        return;
    }
    // decode triangular tile id: bx = row, cy = bid - bx(bx+1)/2, cy in [0, bx]
    int k = bid;
    int bx = (int)((sqrtf(8.0f * (float)k + 1.0f) - 1.0f) * 0.5f);
    while ((bx + 1) * (bx + 2) / 2 <= k) ++bx;
    while (bx * (bx + 1) / 2 > k) --bx;
    const int cy = k - bx * (bx + 1) / 2;
    if (cy == bx) supcon_tile<true >(Fb, part, bx, cy, smem);
    else          supcon_tile<false>(Fb, part, bx, cy, smem);
}

__global__ __launch_bounds__(256) void supcon_finalize(const float* __restrict__ F,
                                                       const int* __restrict__ labels,
                                                       const float* __restrict__ part,
                                                       const float* __restrict__ G,
                                                       const int* __restrict__ hist,
                                                       float* __restrict__ bsums,
                                                       unsigned int* __restrict__ ctr,
                                                       float* __restrict__ out) {
    const int t = threadIdx.x;
    const int i = blockIdx.x * 256 + t;

    float Zm = 0.f;
#pragma unroll 8
    for (int c = 0; c < PSLOTS; ++c) Zm += part[(size_t)c * BN + i];

    const int   lbl = labels[i];
    const float cnt = (float)(hist[lbl] - 1);

    const float4* fr = (const float4*)(F + (size_t)i * DK);
    const float4* gr = (const float4*)(G + lbl * DK);
    float dot = 0.f, nrm = 0.f;
#pragma unroll 8
    for (int k = 0; k < DK / 4; ++k) {
        const float4 av = fr[k], gv = gr[k];
        dot += av.x * gv.x + av.y * gv.y + av.z * gv.z + av.w * gv.w;
        nrm += av.x * av.x + av.y * av.y + av.z * av.z + av.w * av.w;
    }

    // m~ = s_ii/T; exact for any m~ (m-dependence cancels outside the 1e-12 term)
    const float mt = nrm * INV_T;
    const float A  = (dot - nrm) * INV_T;
    float term = 0.f;
    if (cnt > 0.5f)
        term = (A - cnt * mt) / cnt - __logf(1e-12f + Zm * __expf(C40F - mt));

    float sum = term;
#pragma unroll
    for (int h = 1; h < 64; h <<= 1) sum += __shfl_xor(sum, h);
    __shared__ float ss[4];
    if ((t & 63) == 0) ss[t >> 6] = sum;
    __syncthreads();
    if (t == 0) {
        bsums[blockIdx.x] = ss[0] + ss[1] + ss[2] + ss[3];
        __threadfence();
        const unsigned old = atomicAdd(ctr, 1u);
        if (old == (BN / 256) - 1) {   // last block folds the final reduction
            __threadfence();
            float tot = 0.f;
            const volatile float* vb = bsums;
            for (int c = 0; c < BN / 256; ++c) tot += vb[c];
            out[0] = -tot * (1.0f / BN);
        }
    }
}

extern "C" void kernel_launch(void* const* d_in, const int* in_sizes, int n_in,
                              void* d_out, int out_size, void* d_ws, size_t ws_size,
                              hipStream_t stream) {
    const float* F      = (const float*)d_in[0];
    const int*   labels = (const int*)d_in[1];
    // d_in[2] (fac_label) is a no-op in the reference math.
    float* out = (float*)d_out;
    char*  ws  = (char*)d_ws;

    unsigned short* Fb    = (unsigned short*)(ws + OFF_FB);
    float*          part  = (float*)(ws + OFF_PART);
    float*          Gp    = (float*)(ws + OFF_GP);
    int*            histp = (int*)(ws + OFF_HISTP);
    float*          G     = (float*)(ws + OFF_G);
    int*            hist  = (int*)(ws + OFF_HIST);
    float*          bsums = (float*)(ws + OFF_BSUM);
    unsigned int*   ctr   = (unsigned int*)(ws + OFF_CTR);

    prep_kernel<<<PB, 256, 0, stream>>>(F, labels, Fb, part, Gp, histp, ctr);
    supcon_main<<<TILES + RIDERS, 256, 0, stream>>>((const short*)Fb, part,
                                                    Gp, histp, G, hist);
    supcon_finalize<<<BN / 256, 256, 0, stream>>>(F, labels, part, G, hist,
                                                  bsums, ctr, out);
}